// Round 15
// baseline (43.461 us; speedup 1.0000x reference)
//
#include <hip/hip_runtime.h>
#include <hip/hip_bf16.h>

typedef __attribute__((ext_vector_type(8)))  short  short8_t;
typedef __attribute__((ext_vector_type(4)))  float  float4_t;
typedef __attribute__((ext_vector_type(16))) float  f32x16_t;
typedef __attribute__((ext_vector_type(4)))  int    int4_t;
typedef __attribute__((ext_vector_type(2)))  unsigned int uint2_t;

// f32 -> bf16 RNE (bit-twiddle; prepass/fallback)
__device__ __forceinline__ unsigned short f2bf(float f) {
    unsigned int u = __builtin_bit_cast(unsigned int, f);
    u += 0x7FFFu + ((u >> 16) & 1u);
    return (unsigned short)(u >> 16);
}
__device__ __forceinline__ unsigned int cvtpk(float a, float b) {
    return (unsigned int)f2bf(a) | ((unsigned int)f2bf(b) << 16);
}
// HW packed convert (no builtin on gfx950)
__device__ __forceinline__ unsigned int cvtpk_hw(float a, float b) {
    unsigned int r;
    asm("v_cvt_pk_bf16_f32 %0, %1, %2" : "=v"(r) : "v"(a), "v"(b));
    return r;
}
// lane i (i<32) <-> lane i+32: newX=[X.lo,Y.lo], newY=[X.hi,Y.hi]
__device__ __forceinline__ void plane32_swap(unsigned int& a, unsigned int& b) {
    asm("v_permlane32_swap_b32 %0, %1" : "+v"(a), "+v"(b));
}
// pinned 16B loads (compiler cannot sink/reorder vs volatile asm)
__device__ __forceinline__ void gld16(int4_t& d, const void* p) {
    asm volatile("global_load_dwordx4 %0, %1, off" : "=&v"(d) : "v"(p) : "memory");
}
#define GLD16O(d, p, OFF) \
    asm volatile("global_load_dwordx4 %0, %1, off offset:" OFF : "=&v"(d) : "v"(p) : "memory")
// drain current step's 8 W2 loads; keep the (younger) af prefetch in flight
__device__ __forceinline__ void wait1() {
    asm volatile("s_waitcnt vmcnt(1)" ::: "memory");
    __builtin_amdgcn_sched_barrier(0);
}
__device__ __forceinline__ void wait0() {
    asm volatile("s_waitcnt vmcnt(0)" ::: "memory");
    __builtin_amdgcn_sched_barrier(0);
}
__device__ __forceinline__ void sbar() { __builtin_amdgcn_sched_barrier(0); }

// ---- prepass ----
// W2t granule layout (32x32x16 A-frags): granule g = (ks*8+et)*64+lane,
//   value = W2[et*32+(lane&31)][ks*16+(lane>>5)*8 .. +8)  (bf16 x8, 16B)
// W1b: 1024 x 8 bf16 row-major
__global__ void prep_kernel(const float* __restrict__ W2, const float* __restrict__ W1,
                            unsigned short* __restrict__ W2t, unsigned short* __restrict__ W1b) {
    const int bid = blockIdx.x, tid = threadIdx.x;
    if (bid < 128) {
        const int g   = bid * 256 + tid;
        const int l   = g & 63;
        const int pos = g >> 6;                   // ks*8+et
        const int ks  = pos >> 3;
        const int et  = pos & 7;
        const int e   = et * 32 + (l & 31);
        const int f0  = ks * 16 + (l >> 5) * 8;
        const float* src = W2 + (size_t)e * 1024 + f0;
        const float4_t v0 = *reinterpret_cast<const float4_t*>(src);
        const float4_t v1 = *reinterpret_cast<const float4_t*>(src + 4);
        int4_t p;
        p[0] = (int)cvtpk(v0[0], v0[1]);
        p[1] = (int)cvtpk(v0[2], v0[3]);
        p[2] = (int)cvtpk(v1[0], v1[1]);
        p[3] = (int)cvtpk(v1[2], v1[3]);
        *reinterpret_cast<int4_t*>(W2t + (size_t)g * 8) = p;
    } else {
        const int base = tid * 32;
        #pragma unroll
        for (int it = 0; it < 8; ++it) {
            const float4_t v = *reinterpret_cast<const float4_t*>(W1 + base + it * 4);
            uint2_t p;
            p[0] = cvtpk(v[0], v[1]);
            p[1] = cvtpk(v[2], v[3]);
            *reinterpret_cast<uint2_t*>(W1b + base + it * 4) = p;
        }
    }
}

// ---- fused, 32x32x16; wave = 32 rows x 128 cols x K/2 (K-split-2 for occupancy) ----
// Block = 4 waves = 2 tiles x 2 K-halves; LDS f32 reduce at end. 1024 blocks ->
// 3 blocks/CU (3 waves/SIMD). Single-buffered W2 frags; exact counted vmcnt.
template <bool WSOK>
__global__ __launch_bounds__(256, 3)
void ffq_kernel(const float* __restrict__ x,
                const float* __restrict__ theta,
                const float* __restrict__ W1f,
                const unsigned short* __restrict__ W1b,
                const float* __restrict__ W2f,
                const unsigned short* __restrict__ W2t,
                float* __restrict__ out)
{
    __shared__ float red[2][32][132];   // 33792 B; stride 132 -> mild 4-way on b128 (epilogue only)

    const int tid  = threadIdx.x;
    const int lane = tid & 63;
    const int w    = tid >> 6;
    const int bid  = blockIdx.x;
    const int coltile = bid & 1;                  // 2 col-tiles of 128
    const int tloc    = w >> 1;                   // tile within block
    const int khalf   = w & 1;                    // K-half of this wave
    const int mtile   = (bid >> 1) * 2 + tloc;    // 1024 row-tiles of 32
    const int rowbase = mtile * 32;
    const int kb16    = khalf * 16;               // first step index of this K-half
    const int m  = lane & 31;
    const int hi = lane >> 5;

    // ---- q B-frag: lane<32 holds q[rowbase+m][0..7] bf16; hi lanes ZERO (K pad) ----
    short8_t qf = {0,0,0,0,0,0,0,0};
    if (lane < 32) {
        const float* xp = x + (size_t)(rowbase + m) * 256;
        const float4_t x0 = *reinterpret_cast<const float4_t*>(xp);
        const float4_t x1 = *reinterpret_cast<const float4_t*>(xp + 4);
        float qv[8];
        #pragma unroll
        for (int j = 0; j < 4; ++j) {
            qv[j]     = __cosf(x0[j]) * __cosf(theta[j]);
            qv[4 + j] = __cosf(x1[j]) * __cosf(theta[4 + j]);
        }
        int4_t pq;
        pq[0] = (int)cvtpk(qv[0], qv[1]);
        pq[1] = (int)cvtpk(qv[2], qv[3]);
        pq[2] = (int)cvtpk(qv[4], qv[5]);
        pq[3] = (int)cvtpk(qv[6], qv[7]);
        qf = __builtin_bit_cast(short8_t, pq);
    }

    f32x16_t acc0 = {0}, acc1 = {0}, acc2 = {0}, acc3 = {0};
    #pragma unroll
    for (int i = 0; i < 16; ++i) { acc0[i] = 0.f; acc1[i] = 0.f; acc2[i] = 0.f; acc3[i] = 0.f; }

    short8_t bf0, bf1;   // current step's h-derived B-frags (2 k-windows)

    // h-MFMA + relu + in-register transpose (verified R13 network)
    auto htr = [&](short8_t af) {
        const f32x16_t z = acc0 * 0.f;
        const f32x16_t d = __builtin_amdgcn_mfma_f32_32x32x16_bf16(af, qf, z, 0, 0, 0);
        unsigned int U00 = cvtpk_hw(fmaxf(d[0],  0.f), fmaxf(d[1],  0.f));
        unsigned int U01 = cvtpk_hw(fmaxf(d[2],  0.f), fmaxf(d[3],  0.f));
        unsigned int U10 = cvtpk_hw(fmaxf(d[4],  0.f), fmaxf(d[5],  0.f));
        unsigned int U11 = cvtpk_hw(fmaxf(d[6],  0.f), fmaxf(d[7],  0.f));
        unsigned int U20 = cvtpk_hw(fmaxf(d[8],  0.f), fmaxf(d[9],  0.f));
        unsigned int U21 = cvtpk_hw(fmaxf(d[10], 0.f), fmaxf(d[11], 0.f));
        unsigned int U30 = cvtpk_hw(fmaxf(d[12], 0.f), fmaxf(d[13], 0.f));
        unsigned int U31 = cvtpk_hw(fmaxf(d[14], 0.f), fmaxf(d[15], 0.f));
        plane32_swap(U00, U10);
        plane32_swap(U01, U11);
        plane32_swap(U20, U30);
        plane32_swap(U21, U31);
        int4_t p0; p0[0]=(int)U00; p0[1]=(int)U01; p0[2]=(int)U10; p0[3]=(int)U11;
        int4_t p1; p1[0]=(int)U20; p1[1]=(int)U21; p1[2]=(int)U30; p1[3]=(int)U31;
        bf0 = __builtin_bit_cast(short8_t, p0);
        bf1 = __builtin_bit_cast(short8_t, p1);
    };
    // main: acc[et] += W2frag[kw][et] x bf[kw]  (8 MFMA)
    auto main8 = [&](const int4_t& r0, const int4_t& r1, const int4_t& r2, const int4_t& r3,
                     const int4_t& r4, const int4_t& r5, const int4_t& r6, const int4_t& r7) {
        acc0 = __builtin_amdgcn_mfma_f32_32x32x16_bf16(__builtin_bit_cast(short8_t, r0), bf0, acc0, 0, 0, 0);
        acc1 = __builtin_amdgcn_mfma_f32_32x32x16_bf16(__builtin_bit_cast(short8_t, r1), bf0, acc1, 0, 0, 0);
        acc2 = __builtin_amdgcn_mfma_f32_32x32x16_bf16(__builtin_bit_cast(short8_t, r2), bf0, acc2, 0, 0, 0);
        acc3 = __builtin_amdgcn_mfma_f32_32x32x16_bf16(__builtin_bit_cast(short8_t, r3), bf0, acc3, 0, 0, 0);
        acc0 = __builtin_amdgcn_mfma_f32_32x32x16_bf16(__builtin_bit_cast(short8_t, r4), bf1, acc0, 0, 0, 0);
        acc1 = __builtin_amdgcn_mfma_f32_32x32x16_bf16(__builtin_bit_cast(short8_t, r5), bf1, acc1, 0, 0, 0);
        acc2 = __builtin_amdgcn_mfma_f32_32x32x16_bf16(__builtin_bit_cast(short8_t, r6), bf1, acc2, 0, 0, 0);
        acc3 = __builtin_amdgcn_mfma_f32_32x32x16_bf16(__builtin_bit_cast(short8_t, r7), bf1, acc3, 0, 0, 0);
    };

    if constexpr (WSOK) {
        const char* W2b = (const char*)W2t + (size_t)coltile * 4096 + (size_t)lane * 16;
        const char* W1a = (const char*)W1b + (size_t)m * 16;

        int4_t c0,c1,c2,c3,c4,c5,c6,c7;     // single-buffered W2 frags
        int4_t afA, afB;

        #define ISSUE_W2(S) do {                                                 \
            const char* p0_ = W2b + ((size_t)((S) & 31) << 14);                  \
            const char* p1_ = p0_ + 8192;                                        \
            GLD16O(c0, p0_, "0");    GLD16O(c1, p0_, "1024");                    \
            GLD16O(c2, p0_, "2048"); GLD16O(c3, p0_, "3072");                    \
            GLD16O(c4, p1_, "0");    GLD16O(c5, p1_, "1024");                    \
            GLD16O(c6, p1_, "2048"); GLD16O(c7, p1_, "3072"); } while (0)
        #define ISSUE_AF(R, S) gld16(R, W1a + ((size_t)((S) & 31) << 9))

        // prologue: bf(kb16) ready; queue = [W2(kb16) x8, af(kb16+1)]
        ISSUE_AF(afA, kb16);
        wait0();
        htr(__builtin_bit_cast(short8_t, afA));
        ISSUE_W2(kb16);
        ISSUE_AF(afB, kb16 + 1);

        #pragma unroll 1
        for (int k = 0; k < 8; ++k) {
            const int s = kb16 + k * 2;
            // even step s: queue entering = [W2(s) x8 old, af(s+1) young]
            wait1();                                   // W2(s) landed; af still flying
            main8(c0,c1,c2,c3,c4,c5,c6,c7);
            wait0();                                   // af(s+1) landed
            htr(__builtin_bit_cast(short8_t, afB));    // bf(s+1)
            sbar();                                    // MFMA/htr must not sink past reissue
            ISSUE_W2(s + 1);
            ISSUE_AF(afA, s + 2);
            // odd step s+1
            wait1();
            main8(c0,c1,c2,c3,c4,c5,c6,c7);
            wait0();
            htr(__builtin_bit_cast(short8_t, afA));    // bf(s+2) (tail iter: unused)
            sbar();
            ISSUE_W2(s + 2);                           // tail: dangling (drained below)
            ISSUE_AF(afB, s + 3);
        }
        wait0();   // land dangling prefetches before regalloc reuses their regs
        #undef ISSUE_W2
        #undef ISSUE_AF
    } else {
        // fallback: same math, compiler-scheduled loads + on-the-fly cvt
        for (int ss = 0; ss < 16; ++ss) {
            const int s = kb16 + ss;
            const float* ws = W1f + (size_t)(s * 32 + m) * 8;
            const float4_t a0 = *reinterpret_cast<const float4_t*>(ws);
            const float4_t a1 = *reinterpret_cast<const float4_t*>(ws + 4);
            int4_t pa;
            pa[0] = (int)cvtpk(a0[0], a0[1]);
            pa[1] = (int)cvtpk(a0[2], a0[3]);
            pa[2] = (int)cvtpk(a1[0], a1[1]);
            pa[3] = (int)cvtpk(a1[2], a1[3]);
            htr(__builtin_bit_cast(short8_t, pa));
            int4_t fr[8];
            #pragma unroll
            for (int kw = 0; kw < 2; ++kw)
                #pragma unroll
                for (int et = 0; et < 4; ++et) {
                    const int e = coltile * 128 + et * 32 + m;
                    const float* p = W2f + (size_t)e * 1024 + (s * 32 + kw * 16) + hi * 8;
                    const float4_t v0 = *reinterpret_cast<const float4_t*>(p);
                    const float4_t v1 = *reinterpret_cast<const float4_t*>(p + 4);
                    int4_t pb;
                    pb[0] = (int)cvtpk(v0[0], v0[1]);
                    pb[1] = (int)cvtpk(v0[2], v0[3]);
                    pb[2] = (int)cvtpk(v1[0], v1[1]);
                    pb[3] = (int)cvtpk(v1[2], v1[3]);
                    fr[kw * 4 + et] = pb;
                }
            main8(fr[0], fr[1], fr[2], fr[3], fr[4], fr[5], fr[6], fr[7]);
        }
    }

    // ---- K-half reduce via LDS (symmetric indexing), then store (khalf 0) ----
    // acc element (et, 4*rq+j) lives at output col et*32 + hi*4 + rq*8 + j of row m.
    #define RED_W(ACC, ET) do {                                                   \
        _Pragma("unroll")                                                         \
        for (int rq = 0; rq < 4; ++rq) {                                          \
            float4_t v;                                                           \
            v[0] = ACC[4*rq+0]; v[1] = ACC[4*rq+1];                               \
            v[2] = ACC[4*rq+2]; v[3] = ACC[4*rq+3];                               \
            *reinterpret_cast<float4_t*>(&red[tloc][m][(ET)*32 + hi*4 + rq*8]) = v; \
        } } while (0)
    #define RED_R(ACC, ET) do {                                                   \
        _Pragma("unroll")                                                         \
        for (int rq = 0; rq < 4; ++rq) {                                          \
            const float4_t v = *reinterpret_cast<const float4_t*>(                \
                &red[tloc][m][(ET)*32 + hi*4 + rq*8]);                            \
            ACC[4*rq+0] += v[0]; ACC[4*rq+1] += v[1];                             \
            ACC[4*rq+2] += v[2]; ACC[4*rq+3] += v[3];                             \
        } } while (0)

    if (khalf) {
        RED_W(acc0, 0); RED_W(acc1, 1); RED_W(acc2, 2); RED_W(acc3, 3);
    }
    __syncthreads();
    if (!khalf) {
        RED_R(acc0, 0); RED_R(acc1, 1); RED_R(acc2, 2); RED_R(acc3, 3);
        float* orow = out + (size_t)(rowbase + m) * 256 + coltile * 128 + hi * 4;
        #define STORE_ET(ACC, ET) do {                                            \
            _Pragma("unroll")                                                     \
            for (int rq = 0; rq < 4; ++rq) {                                      \
                float4_t v;                                                       \
                v[0] = ACC[4*rq+0]; v[1] = ACC[4*rq+1];                           \
                v[2] = ACC[4*rq+2]; v[3] = ACC[4*rq+3];                           \
                *reinterpret_cast<float4_t*>(orow + (ET) * 32 + rq * 8) = v;      \
            } } while (0)
        STORE_ET(acc0, 0);
        STORE_ET(acc1, 1);
        STORE_ET(acc2, 2);
        STORE_ET(acc3, 3);
        #undef STORE_ET
    }
    #undef RED_W
    #undef RED_R
}

extern "C" void kernel_launch(void* const* d_in, const int* in_sizes, int n_in,
                              void* d_out, int out_size, void* d_ws, size_t ws_size,
                              hipStream_t stream) {
    const float* x     = (const float*)d_in[0];   // [8,4096,256]
    const float* theta = (const float*)d_in[1];   // [8]
    const float* W1    = (const float*)d_in[2];   // [1024,8]
    const float* W2    = (const float*)d_in[3];   // [256,1024]
    float* out = (float*)d_out;                   // [8,4096,256] f32

    const size_t need = (size_t)(256 * 1024 + 1024 * 8) * sizeof(unsigned short);
    const bool wsok = (ws_size >= need);

    if (wsok) {
        unsigned short* W2t = (unsigned short*)d_ws;   // 512KB, 32x32x16-A granule layout
        unsigned short* W1b = W2t + 256 * 1024;        // 16KB bf16
        prep_kernel<<<129, 256, 0, stream>>>(W2, W1, W2t, W1b);
        ffq_kernel<true><<<1024, 256, 0, stream>>>(x, theta, nullptr, W1b, nullptr, W2t, out);
    } else {
        ffq_kernel<false><<<1024, 256, 0, stream>>>(x, theta, W1, nullptr, W2, nullptr, out);
    }
}

// Round 16
// 41.904 us; speedup vs baseline: 1.0372x; 1.0372x over previous
//
#include <hip/hip_runtime.h>
#include <hip/hip_bf16.h>

typedef __attribute__((ext_vector_type(8)))  short  short8_t;
typedef __attribute__((ext_vector_type(4)))  float  float4_t;
typedef __attribute__((ext_vector_type(16))) float  f32x16_t;
typedef __attribute__((ext_vector_type(4)))  int    int4_t;
typedef __attribute__((ext_vector_type(2)))  unsigned int uint2_t;

// f32 -> bf16 RNE (bit-twiddle; prepass/fallback)
__device__ __forceinline__ unsigned short f2bf(float f) {
    unsigned int u = __builtin_bit_cast(unsigned int, f);
    u += 0x7FFFu + ((u >> 16) & 1u);
    return (unsigned short)(u >> 16);
}
__device__ __forceinline__ unsigned int cvtpk(float a, float b) {
    return (unsigned int)f2bf(a) | ((unsigned int)f2bf(b) << 16);
}
// HW packed convert (no builtin on gfx950)
__device__ __forceinline__ unsigned int cvtpk_hw(float a, float b) {
    unsigned int r;
    asm("v_cvt_pk_bf16_f32 %0, %1, %2" : "=v"(r) : "v"(a), "v"(b));
    return r;
}
// lane i (i<32) <-> lane i+32: newX=[X.lo,Y.lo], newY=[X.hi,Y.hi]
__device__ __forceinline__ void plane32_swap(unsigned int& a, unsigned int& b) {
    asm("v_permlane32_swap_b32 %0, %1" : "+v"(a), "+v"(b));
}
// global -> LDS direct staging, 16B/lane (dest = uniform base + lane*16)
__device__ __forceinline__ void gload_lds16(const void* g, void* l) {
    __builtin_amdgcn_global_load_lds(
        (const __attribute__((address_space(1))) void*)g,
        (__attribute__((address_space(3))) void*)l, 16, 0, 0);
}

// ---- prepass (verified R13) ----
// W2t granule layout (32x32x16 A-frags): granule g = (ks*8+et)*64+lane,
//   value = W2[et*32+(lane&31)][ks*16+(lane>>5)*8 .. +8)  (bf16 x8, 16B)
// W1b: 1024 x 8 bf16 row-major
__global__ void prep_kernel(const float* __restrict__ W2, const float* __restrict__ W1,
                            unsigned short* __restrict__ W2t, unsigned short* __restrict__ W1b) {
    const int bid = blockIdx.x, tid = threadIdx.x;
    if (bid < 128) {
        const int g   = bid * 256 + tid;
        const int l   = g & 63;
        const int pos = g >> 6;                   // ks*8+et
        const int ks  = pos >> 3;
        const int et  = pos & 7;
        const int e   = et * 32 + (l & 31);
        const int f0  = ks * 16 + (l >> 5) * 8;
        const float* src = W2 + (size_t)e * 1024 + f0;
        const float4_t v0 = *reinterpret_cast<const float4_t*>(src);
        const float4_t v1 = *reinterpret_cast<const float4_t*>(src + 4);
        int4_t p;
        p[0] = (int)cvtpk(v0[0], v0[1]);
        p[1] = (int)cvtpk(v0[2], v0[3]);
        p[2] = (int)cvtpk(v1[0], v1[1]);
        p[3] = (int)cvtpk(v1[2], v1[3]);
        *reinterpret_cast<int4_t*>(W2t + (size_t)g * 8) = p;
    } else {
        const int base = tid * 32;
        #pragma unroll
        for (int it = 0; it < 8; ++it) {
            const float4_t v = *reinterpret_cast<const float4_t*>(W1 + base + it * 4);
            uint2_t p;
            p[0] = cvtpk(v[0], v[1]);
            p[1] = cvtpk(v[2], v[3]);
            *reinterpret_cast<uint2_t*>(W1b + base + it * 4) = p;
        }
    }
}

// ---- fused, LDS-shared fragments, 32x32x16; wave = 32 rows x 64 cols, full K ----
// Block = 4 waves = 4 rowtiles x ONE shared coltile: W2 staged global->LDS once per
// block per step (4KB, dbuf), W1 staged once (16KB). 1024 blocks -> 4 blocks/CU,
// 16 waves/CU. One barrier per step. All frag math identical to verified R13.
template <bool WSOK>
__global__ __launch_bounds__(256, 4)
void ffq_kernel(const float* __restrict__ x,
                const float* __restrict__ theta,
                const float* __restrict__ W1f,
                const unsigned short* __restrict__ W1b,
                const float* __restrict__ W2f,
                const unsigned short* __restrict__ W2t,
                float* __restrict__ out)
{
    __shared__ __align__(16) unsigned short W1L[1024 * 8];    // 16 KB (full W1b)
    __shared__ __align__(16) unsigned short W2L[2][4][512];   //  8 KB (dbuf x 4 frags x 1KB)

    const int tid  = threadIdx.x;
    const int lane = tid & 63;
    const int w    = tid >> 6;
    const int bid  = blockIdx.x;
    const int ct      = bid & 3;                  // coltile (64 cols), shared by block
    const int rowbase = (bid >> 2) * 128 + w * 32;
    const int m  = lane & 31;
    const int hi = lane >> 5;

    // ---- q B-frag: lane<32 holds q[rowbase+m][0..7] bf16; hi lanes ZERO (K pad) ----
    short8_t qf = {0,0,0,0,0,0,0,0};
    if (lane < 32) {
        const float* xp = x + (size_t)(rowbase + m) * 256;
        const float4_t x0 = *reinterpret_cast<const float4_t*>(xp);
        const float4_t x1 = *reinterpret_cast<const float4_t*>(xp + 4);
        float qv[8];
        #pragma unroll
        for (int j = 0; j < 4; ++j) {
            qv[j]     = __cosf(x0[j]) * __cosf(theta[j]);
            qv[4 + j] = __cosf(x1[j]) * __cosf(theta[4 + j]);
        }
        int4_t pq;
        pq[0] = (int)cvtpk(qv[0], qv[1]);
        pq[1] = (int)cvtpk(qv[2], qv[3]);
        pq[2] = (int)cvtpk(qv[4], qv[5]);
        pq[3] = (int)cvtpk(qv[6], qv[7]);
        qf = __builtin_bit_cast(short8_t, pq);
    }

    f32x16_t acc0 = {0}, acc1 = {0};
    #pragma unroll
    for (int i = 0; i < 16; ++i) { acc0[i] = 0.f; acc1[i] = 0.f; }

    short8_t bf0, bf1;

    // h-MFMA + relu + in-register transpose (verified R13 network)
    auto htr = [&](short8_t af) {
        const f32x16_t z = acc0 * 0.f;
        const f32x16_t d = __builtin_amdgcn_mfma_f32_32x32x16_bf16(af, qf, z, 0, 0, 0);
        unsigned int U00 = cvtpk_hw(fmaxf(d[0],  0.f), fmaxf(d[1],  0.f));
        unsigned int U01 = cvtpk_hw(fmaxf(d[2],  0.f), fmaxf(d[3],  0.f));
        unsigned int U10 = cvtpk_hw(fmaxf(d[4],  0.f), fmaxf(d[5],  0.f));
        unsigned int U11 = cvtpk_hw(fmaxf(d[6],  0.f), fmaxf(d[7],  0.f));
        unsigned int U20 = cvtpk_hw(fmaxf(d[8],  0.f), fmaxf(d[9],  0.f));
        unsigned int U21 = cvtpk_hw(fmaxf(d[10], 0.f), fmaxf(d[11], 0.f));
        unsigned int U30 = cvtpk_hw(fmaxf(d[12], 0.f), fmaxf(d[13], 0.f));
        unsigned int U31 = cvtpk_hw(fmaxf(d[14], 0.f), fmaxf(d[15], 0.f));
        plane32_swap(U00, U10);
        plane32_swap(U01, U11);
        plane32_swap(U20, U30);
        plane32_swap(U21, U31);
        int4_t p0; p0[0]=(int)U00; p0[1]=(int)U01; p0[2]=(int)U10; p0[3]=(int)U11;
        int4_t p1; p1[0]=(int)U20; p1[1]=(int)U21; p1[2]=(int)U30; p1[3]=(int)U31;
        bf0 = __builtin_bit_cast(short8_t, p0);
        bf1 = __builtin_bit_cast(short8_t, p1);
    };

    if constexpr (WSOK) {
        const char* W2tb = (const char*)W2t;
        const char* W1bb = (const char*)W1b;

        // ---- prologue staging: full W1b (wave w: insts w,w+4,w+8,w+12) + W2 step 0 ----
        #pragma unroll
        for (int i = 0; i < 4; ++i) {
            const int blk = w + i * 4;
            gload_lds16(W1bb + (size_t)blk * 1024 + (size_t)lane * 16, &W1L[blk * 512]);
        }
        {   // wave w stages frag w of step 0: kw=w>>1, et=w&1; g=(0*2+kw)*8 + 2*ct + (w&1)
            const int g0 = ((w >> 1) * 8) + 2 * ct + (w & 1);
            gload_lds16(W2tb + (size_t)g0 * 1024 + (size_t)lane * 16, &W2L[0][w][0]);
        }

        #pragma unroll 2
        for (int s = 0; s < 32; ++s) {
            const int cur = s & 1;
            __syncthreads();   // drains staging for step s; prior reads of buf cur^1 done

            if (s + 1 < 32) {  // wave w stages frag w of step s+1
                const int g = ((2 * (s + 1) + (w >> 1)) * 8) + 2 * ct + (w & 1);
                gload_lds16(W2tb + (size_t)g * 1024 + (size_t)lane * 16, &W2L[cur ^ 1][w][0]);
            }

            // A-frag (W1) + W2 frags from LDS
            const short8_t af = *reinterpret_cast<const short8_t*>(&W1L[(s * 32 + m) * 8]);
            const short8_t c0 = *reinterpret_cast<const short8_t*>(&W2L[cur][0][lane * 8]);
            const short8_t c1 = *reinterpret_cast<const short8_t*>(&W2L[cur][1][lane * 8]);
            const short8_t c2 = *reinterpret_cast<const short8_t*>(&W2L[cur][2][lane * 8]);
            const short8_t c3 = *reinterpret_cast<const short8_t*>(&W2L[cur][3][lane * 8]);

            htr(af);           // bf0, bf1 for this step

            acc0 = __builtin_amdgcn_mfma_f32_32x32x16_bf16(c0, bf0, acc0, 0, 0, 0);
            acc1 = __builtin_amdgcn_mfma_f32_32x32x16_bf16(c1, bf0, acc1, 0, 0, 0);
            acc0 = __builtin_amdgcn_mfma_f32_32x32x16_bf16(c2, bf1, acc0, 0, 0, 0);
            acc1 = __builtin_amdgcn_mfma_f32_32x32x16_bf16(c3, bf1, acc1, 0, 0, 0);
        }
    } else {
        // fallback: same math, compiler-scheduled global loads + on-the-fly cvt (no LDS)
        for (int s = 0; s < 32; ++s) {
            const float* ws = W1f + (size_t)(s * 32 + m) * 8;
            const float4_t a0 = *reinterpret_cast<const float4_t*>(ws);
            const float4_t a1 = *reinterpret_cast<const float4_t*>(ws + 4);
            int4_t pa;
            pa[0] = (int)cvtpk(a0[0], a0[1]);
            pa[1] = (int)cvtpk(a0[2], a0[3]);
            pa[2] = (int)cvtpk(a1[0], a1[1]);
            pa[3] = (int)cvtpk(a1[2], a1[3]);
            htr(__builtin_bit_cast(short8_t, pa));
            int4_t fr[4];
            #pragma unroll
            for (int kw = 0; kw < 2; ++kw)
                #pragma unroll
                for (int et = 0; et < 2; ++et) {
                    const int e = ct * 64 + et * 32 + m;
                    const float* p = W2f + (size_t)e * 1024 + (s * 32 + kw * 16) + hi * 8;
                    const float4_t v0 = *reinterpret_cast<const float4_t*>(p);
                    const float4_t v1 = *reinterpret_cast<const float4_t*>(p + 4);
                    int4_t pb;
                    pb[0] = (int)cvtpk(v0[0], v0[1]);
                    pb[1] = (int)cvtpk(v0[2], v0[3]);
                    pb[2] = (int)cvtpk(v1[0], v1[1]);
                    pb[3] = (int)cvtpk(v1[2], v1[3]);
                    fr[kw * 2 + et] = pb;
                }
            const short8_t f0 = __builtin_bit_cast(short8_t, fr[0]);
            const short8_t f1 = __builtin_bit_cast(short8_t, fr[1]);
            const short8_t f2 = __builtin_bit_cast(short8_t, fr[2]);
            const short8_t f3 = __builtin_bit_cast(short8_t, fr[3]);
            acc0 = __builtin_amdgcn_mfma_f32_32x32x16_bf16(f0, bf0, acc0, 0, 0, 0);
            acc1 = __builtin_amdgcn_mfma_f32_32x32x16_bf16(f1, bf0, acc1, 0, 0, 0);
            acc0 = __builtin_amdgcn_mfma_f32_32x32x16_bf16(f2, bf1, acc0, 0, 0, 0);
            acc1 = __builtin_amdgcn_mfma_f32_32x32x16_bf16(f3, bf1, acc1, 0, 0, 0);
        }
    }

    // ---- epilogue: out^T store. D[e][m]: col m=lane&31, e=(reg&3)+8(reg>>2)+4hi ----
    {
        float* orow = out + (size_t)(rowbase + m) * 256 + ct * 64 + hi * 4;
        #define STORE_ET(ACC, ET) do {                                            \
            _Pragma("unroll")                                                     \
            for (int rq = 0; rq < 4; ++rq) {                                      \
                float4_t v;                                                       \
                v[0] = ACC[4*rq+0]; v[1] = ACC[4*rq+1];                           \
                v[2] = ACC[4*rq+2]; v[3] = ACC[4*rq+3];                           \
                *reinterpret_cast<float4_t*>(orow + (ET) * 32 + rq * 8) = v;      \
            } } while (0)
        STORE_ET(acc0, 0);
        STORE_ET(acc1, 1);
        #undef STORE_ET
    }
}

extern "C" void kernel_launch(void* const* d_in, const int* in_sizes, int n_in,
                              void* d_out, int out_size, void* d_ws, size_t ws_size,
                              hipStream_t stream) {
    const float* x     = (const float*)d_in[0];   // [8,4096,256]
    const float* theta = (const float*)d_in[1];   // [8]
    const float* W1    = (const float*)d_in[2];   // [1024,8]
    const float* W2    = (const float*)d_in[3];   // [256,1024]
    float* out = (float*)d_out;                   // [8,4096,256] f32

    const size_t need = (size_t)(256 * 1024 + 1024 * 8) * sizeof(unsigned short);
    const bool wsok = (ws_size >= need);

    if (wsok) {
        unsigned short* W2t = (unsigned short*)d_ws;   // 512KB, 32x32x16-A granule layout
        unsigned short* W1b = W2t + 256 * 1024;        // 16KB bf16
        prep_kernel<<<129, 256, 0, stream>>>(W2, W1, W2t, W1b);
        ffq_kernel<true><<<1024, 256, 0, stream>>>(x, theta, nullptr, W1b, nullptr, W2t, out);
    } else {
        ffq_kernel<false><<<1024, 256, 0, stream>>>(x, theta, W1, nullptr, W2, nullptr, out);
    }
}

// Round 17
// 39.522 us; speedup vs baseline: 1.0997x; 1.0603x over previous
//
#include <hip/hip_runtime.h>
#include <hip/hip_bf16.h>

typedef __attribute__((ext_vector_type(8)))  short  short8_t;
typedef __attribute__((ext_vector_type(4)))  float  float4_t;
typedef __attribute__((ext_vector_type(16))) float  f32x16_t;
typedef __attribute__((ext_vector_type(4)))  int    int4_t;
typedef __attribute__((ext_vector_type(2)))  unsigned int uint2_t;

// f32 -> bf16 RNE (bit-twiddle; prepass/fallback)
__device__ __forceinline__ unsigned short f2bf(float f) {
    unsigned int u = __builtin_bit_cast(unsigned int, f);
    u += 0x7FFFu + ((u >> 16) & 1u);
    return (unsigned short)(u >> 16);
}
__device__ __forceinline__ unsigned int cvtpk(float a, float b) {
    return (unsigned int)f2bf(a) | ((unsigned int)f2bf(b) << 16);
}
// HW packed convert (no builtin on gfx950)
__device__ __forceinline__ unsigned int cvtpk_hw(float a, float b) {
    unsigned int r;
    asm("v_cvt_pk_bf16_f32 %0, %1, %2" : "=v"(r) : "v"(a), "v"(b));
    return r;
}
// lane i (i<32) <-> lane i+32 (fallback path only)
__device__ __forceinline__ void plane32_swap(unsigned int& a, unsigned int& b) {
    asm("v_permlane32_swap_b32 %0, %1" : "+v"(a), "+v"(b));
}

// ---- prepass (verified R13) ----
// W2t granule layout (32x32x16 A-frags): granule g = (ks*8+et)*64+lane,
//   value = W2[et*32+(lane&31)][ks*16+(lane>>5)*8 .. +8)  (bf16 x8, 16B)
// W1b: 1024 x 8 bf16 row-major
__global__ void prep_kernel(const float* __restrict__ W2, const float* __restrict__ W1,
                            unsigned short* __restrict__ W2t, unsigned short* __restrict__ W1b) {
    const int bid = blockIdx.x, tid = threadIdx.x;
    if (bid < 128) {
        const int g   = bid * 256 + tid;
        const int l   = g & 63;
        const int pos = g >> 6;                   // ks*8+et
        const int ks  = pos >> 3;
        const int et  = pos & 7;
        const int e   = et * 32 + (l & 31);
        const int f0  = ks * 16 + (l >> 5) * 8;
        const float* src = W2 + (size_t)e * 1024 + f0;
        const float4_t v0 = *reinterpret_cast<const float4_t*>(src);
        const float4_t v1 = *reinterpret_cast<const float4_t*>(src + 4);
        int4_t p;
        p[0] = (int)cvtpk(v0[0], v0[1]);
        p[1] = (int)cvtpk(v0[2], v0[3]);
        p[2] = (int)cvtpk(v1[0], v1[1]);
        p[3] = (int)cvtpk(v1[2], v1[3]);
        *reinterpret_cast<int4_t*>(W2t + (size_t)g * 8) = p;
    } else {
        const int base = tid * 32;
        #pragma unroll
        for (int it = 0; it < 8; ++it) {
            const float4_t v = *reinterpret_cast<const float4_t*>(W1 + base + it * 4);
            uint2_t p;
            p[0] = cvtpk(v[0], v[1]);
            p[1] = cvtpk(v[2], v[3]);
            *reinterpret_cast<uint2_t*>(W1b + base + it * 4) = p;
        }
    }
}

// ---- fused; h computed ONCE per 32-row block (redundancy 1), K in 4 chunks ----
// Block = 4 waves = 32 rows x 256 cols. Per chunk (256 f): h-phase (2 h-MFMA/wave,
// cvt_pk + ds_write straight into B-frag granule layout — no permlane), barrier,
// then pure streaming main loop: 16 x {ds_read_b128 + 2 L2 loads + 2 MFMA}.
// LDS 16 KB -> 4 blocks/CU (16 waves/CU), entire grid co-resident.
template <bool WSOK>
__global__ __launch_bounds__(256, 4)
void ffq_kernel(const float* __restrict__ x,
                const float* __restrict__ theta,
                const float* __restrict__ W1f,
                const unsigned short* __restrict__ W1b,
                const float* __restrict__ W2f,
                const unsigned short* __restrict__ W2t,
                float* __restrict__ out)
{
    // h chunk buffer: granule gidx<32 (= local ks*2 + khalf), m<32, 8 bf16 (16B)
    __shared__ __align__(16) unsigned short hL[32 * 32 * 8];   // 16 KB

    const int tid  = threadIdx.x;
    const int lane = tid & 63;
    const int w    = tid >> 6;
    const int bid  = blockIdx.x;
    const int rowbase = bid * 32;                 // 1024 blocks x 32 rows
    const int m  = lane & 31;
    const int hi = lane >> 5;

    // ---- q B-frag: lane<32 holds q[rowbase+m][0..7] bf16; hi lanes ZERO (K pad) ----
    short8_t qf = {0,0,0,0,0,0,0,0};
    if (lane < 32) {
        const float* xp = x + (size_t)(rowbase + m) * 256;
        const float4_t x0 = *reinterpret_cast<const float4_t*>(xp);
        const float4_t x1 = *reinterpret_cast<const float4_t*>(xp + 4);
        float qv[8];
        #pragma unroll
        for (int j = 0; j < 4; ++j) {
            qv[j]     = __cosf(x0[j]) * __cosf(theta[j]);
            qv[4 + j] = __cosf(x1[j]) * __cosf(theta[4 + j]);
        }
        int4_t pq;
        pq[0] = (int)cvtpk(qv[0], qv[1]);
        pq[1] = (int)cvtpk(qv[2], qv[3]);
        pq[2] = (int)cvtpk(qv[4], qv[5]);
        pq[3] = (int)cvtpk(qv[6], qv[7]);
        qf = __builtin_bit_cast(short8_t, pq);
    }

    f32x16_t acc0 = {0}, acc1 = {0};
    #pragma unroll
    for (int i = 0; i < 16; ++i) { acc0[i] = 0.f; acc1[i] = 0.f; }
    f32x16_t zz = acc0;   // zero C-operand for h-MFMA

    if constexpr (WSOK) {
        #pragma unroll 1
        for (int c = 0; c < 4; ++c) {
            __syncthreads();   // previous chunk's reads of hL complete

            // ---- h-phase: wave w computes f-tiles ftl = 2w, 2w+1 of this chunk ----
            #pragma unroll
            for (int i = 0; i < 2; ++i) {
                const int ftl = w * 2 + i;                 // local f-tile 0..7
                const int ftg = c * 8 + ftl;               // global f-tile 0..31
                // A-frag: A[f=ftg*32+m][k=hi*8+j]; hi=1 reads next row (finite,
                // annihilated by qf's zero hi-k) — 16B per lane from L2.
                const short8_t af = *reinterpret_cast<const short8_t*>(
                    (const char*)W1b + (size_t)(ftg * 32 + m) * 16 + hi * 16);
                const f32x16_t d = __builtin_amdgcn_mfma_f32_32x32x16_bf16(af, qf, zz, 0, 0, 0);
                // D[f',m]: f' = (r&3) + 8*(r>>2) + 4*hi. Block b (=f'>>3): lane hi
                // holds j=4*hi..4*hi+3 -> ds_write_b64 at granule(ftl*4+b, m)+hi*8.
                #pragma unroll
                for (int b = 0; b < 4; ++b) {
                    uint2_t pk;
                    pk[0] = cvtpk_hw(fmaxf(d[4*b+0], 0.f), fmaxf(d[4*b+1], 0.f));
                    pk[1] = cvtpk_hw(fmaxf(d[4*b+2], 0.f), fmaxf(d[4*b+3], 0.f));
                    *reinterpret_cast<uint2_t*>(
                        &hL[((ftl * 4 + b) * 32 + m) * 8 + hi * 4]) = pk;
                }
            }

            __syncthreads();   // h chunk published

            // ---- main loop: pure {ds_read, 2 L2 loads, 2 MFMA} x 16 ----
            #pragma unroll 4
            for (int ksl = 0; ksl < 16; ++ksl) {
                const short8_t bf = *reinterpret_cast<const short8_t*>(
                    &hL[((ksl * 2 + hi) * 32 + m) * 8]);
                const int ks = c * 16 + ksl;
                const short8_t a0 = *reinterpret_cast<const short8_t*>(
                    W2t + (size_t)(ks * 8 + 2 * w)     * 512 + lane * 8);
                const short8_t a1 = *reinterpret_cast<const short8_t*>(
                    W2t + (size_t)(ks * 8 + 2 * w + 1) * 512 + lane * 8);
                acc0 = __builtin_amdgcn_mfma_f32_32x32x16_bf16(a0, bf, acc0, 0, 0, 0);
                acc1 = __builtin_amdgcn_mfma_f32_32x32x16_bf16(a1, bf, acc1, 0, 0, 0);
            }
        }
    } else {
        // fallback (no workspace): register-direct per-step htr (R16-verified form)
        short8_t bf0, bf1;
        auto htr = [&](short8_t af) {
            const f32x16_t d = __builtin_amdgcn_mfma_f32_32x32x16_bf16(af, qf, zz, 0, 0, 0);
            unsigned int U00 = cvtpk_hw(fmaxf(d[0],  0.f), fmaxf(d[1],  0.f));
            unsigned int U01 = cvtpk_hw(fmaxf(d[2],  0.f), fmaxf(d[3],  0.f));
            unsigned int U10 = cvtpk_hw(fmaxf(d[4],  0.f), fmaxf(d[5],  0.f));
            unsigned int U11 = cvtpk_hw(fmaxf(d[6],  0.f), fmaxf(d[7],  0.f));
            unsigned int U20 = cvtpk_hw(fmaxf(d[8],  0.f), fmaxf(d[9],  0.f));
            unsigned int U21 = cvtpk_hw(fmaxf(d[10], 0.f), fmaxf(d[11], 0.f));
            unsigned int U30 = cvtpk_hw(fmaxf(d[12], 0.f), fmaxf(d[13], 0.f));
            unsigned int U31 = cvtpk_hw(fmaxf(d[14], 0.f), fmaxf(d[15], 0.f));
            plane32_swap(U00, U10);
            plane32_swap(U01, U11);
            plane32_swap(U20, U30);
            plane32_swap(U21, U31);
            int4_t p0; p0[0]=(int)U00; p0[1]=(int)U01; p0[2]=(int)U10; p0[3]=(int)U11;
            int4_t p1; p1[0]=(int)U20; p1[1]=(int)U21; p1[2]=(int)U30; p1[3]=(int)U31;
            bf0 = __builtin_bit_cast(short8_t, p0);
            bf1 = __builtin_bit_cast(short8_t, p1);
        };
        for (int s = 0; s < 32; ++s) {
            const float* ws = W1f + (size_t)(s * 32 + m) * 8;
            const float4_t a0 = *reinterpret_cast<const float4_t*>(ws);
            const float4_t a1 = *reinterpret_cast<const float4_t*>(ws + 4);
            int4_t pa;
            pa[0] = (int)cvtpk(a0[0], a0[1]);
            pa[1] = (int)cvtpk(a0[2], a0[3]);
            pa[2] = (int)cvtpk(a1[0], a1[1]);
            pa[3] = (int)cvtpk(a1[2], a1[3]);
            htr(__builtin_bit_cast(short8_t, pa));
            int4_t fr[4];
            #pragma unroll
            for (int kw = 0; kw < 2; ++kw)
                #pragma unroll
                for (int et = 0; et < 2; ++et) {
                    const int e = w * 64 + et * 32 + m;
                    const float* p = W2f + (size_t)e * 1024 + (s * 32 + kw * 16) + hi * 8;
                    const float4_t v0 = *reinterpret_cast<const float4_t*>(p);
                    const float4_t v1 = *reinterpret_cast<const float4_t*>(p + 4);
                    int4_t pb;
                    pb[0] = (int)cvtpk(v0[0], v0[1]);
                    pb[1] = (int)cvtpk(v0[2], v0[3]);
                    pb[2] = (int)cvtpk(v1[0], v1[1]);
                    pb[3] = (int)cvtpk(v1[2], v1[3]);
                    fr[kw * 2 + et] = pb;
                }
            const short8_t f0 = __builtin_bit_cast(short8_t, fr[0]);
            const short8_t f1 = __builtin_bit_cast(short8_t, fr[1]);
            const short8_t f2 = __builtin_bit_cast(short8_t, fr[2]);
            const short8_t f3 = __builtin_bit_cast(short8_t, fr[3]);
            acc0 = __builtin_amdgcn_mfma_f32_32x32x16_bf16(f0, bf0, acc0, 0, 0, 0);
            acc1 = __builtin_amdgcn_mfma_f32_32x32x16_bf16(f1, bf0, acc1, 0, 0, 0);
            acc0 = __builtin_amdgcn_mfma_f32_32x32x16_bf16(f2, bf1, acc0, 0, 0, 0);
            acc1 = __builtin_amdgcn_mfma_f32_32x32x16_bf16(f3, bf1, acc1, 0, 0, 0);
        }
    }

    // ---- epilogue: out^T store (verified R13/R16). D[e][m]: col m, e=(r&3)+8(r>>2)+4hi ----
    {
        float* orow = out + (size_t)(rowbase + m) * 256 + w * 64 + hi * 4;
        #define STORE_ET(ACC, ET) do {                                            \
            _Pragma("unroll")                                                     \
            for (int rq = 0; rq < 4; ++rq) {                                      \
                float4_t v;                                                       \
                v[0] = ACC[4*rq+0]; v[1] = ACC[4*rq+1];                           \
                v[2] = ACC[4*rq+2]; v[3] = ACC[4*rq+3];                           \
                *reinterpret_cast<float4_t*>(orow + (ET) * 32 + rq * 8) = v;      \
            } } while (0)
        STORE_ET(acc0, 0);
        STORE_ET(acc1, 1);
        #undef STORE_ET
    }
}

extern "C" void kernel_launch(void* const* d_in, const int* in_sizes, int n_in,
                              void* d_out, int out_size, void* d_ws, size_t ws_size,
                              hipStream_t stream) {
    const float* x     = (const float*)d_in[0];   // [8,4096,256]
    const float* theta = (const float*)d_in[1];   // [8]
    const float* W1    = (const float*)d_in[2];   // [1024,8]
    const float* W2    = (const float*)d_in[3];   // [256,1024]
    float* out = (float*)d_out;                   // [8,4096,256] f32

    // need W2t (512KB) + W1b (16KB) + 16B slack for the hi=1 tail read
    const size_t need = (size_t)(256 * 1024 + 1024 * 8) * sizeof(unsigned short) + 16;
    const bool wsok = (ws_size >= need);

    if (wsok) {
        unsigned short* W2t = (unsigned short*)d_ws;   // 512KB, 32x32x16-A granule layout
        unsigned short* W1b = W2t + 256 * 1024;        // 16KB bf16
        prep_kernel<<<129, 256, 0, stream>>>(W2, W1, W2t, W1b);
        ffq_kernel<true><<<1024, 256, 0, stream>>>(x, theta, nullptr, W1b, nullptr, W2t, out);
    } else {
        ffq_kernel<false><<<1024, 256, 0, stream>>>(x, theta, W1, nullptr, W2, nullptr, out);
    }
}